// Round 5
// baseline (967.825 us; speedup 1.0000x reference)
//
#include <hip/hip_runtime.h>
#include <hip/hip_bf16.h>

#define DEVFN __device__ __forceinline__

constexpr int Bb = 4, Nn = 2048, Dd = 512, Hh = 8, DVv = 64, DOo = 512;

typedef short short8 __attribute__((ext_vector_type(8)));
typedef float f32x4 __attribute__((ext_vector_type(4)));

typedef __attribute__((address_space(1))) void GV;   // global
typedef __attribute__((address_space(3))) void LV;   // LDS

DEVFN unsigned short f32_bf16(float f) {
  unsigned u = __builtin_bit_cast(unsigned, f);
  u += 0x7fffu + ((u >> 16) & 1u);          // RNE
  return (unsigned short)(u >> 16);
}

DEVFN void barrier_raw() {
  asm volatile("" ::: "memory");
  __builtin_amdgcn_s_barrier();
  asm volatile("" ::: "memory");
}

template<int Nv> DEVFN void wait_vmcnt() {
  if constexpr (Nv == 0)       asm volatile("s_waitcnt vmcnt(0)"  ::: "memory");
  else if constexpr (Nv == 6)  asm volatile("s_waitcnt vmcnt(6)"  ::: "memory");
  else if constexpr (Nv == 8)  asm volatile("s_waitcnt vmcnt(8)"  ::: "memory");
  else if constexpr (Nv == 10) asm volatile("s_waitcnt vmcnt(10)" ::: "memory");
  else static_assert(Nv == 0 || Nv == 6 || Nv == 8 || Nv == 10, "bad vmcnt");
}
DEVFN void wait_lgkm0() { asm volatile("s_waitcnt lgkmcnt(0)" ::: "memory"); }

// Stage TOTAL bytes into LDS. Linear LDS dest (required by global_load_lds),
// XOR-swizzled GLOBAL source so a swizzled ds_read is conflict-free:
// LDS(row,blk) holds global(row, blk ^ (row & min(nblk-1,7))).
template<int ROWBYTES, int TOTAL, int NTHR = 256>
DEVFN void stage_tile(const char* g, int strideBytes, char* lds, int tid) {
  constexpr int MASK = (ROWBYTES >> 4) - 1;
#pragma unroll
  for (int off = 0; off < TOTAL; off += NTHR * 16) {
    int o   = off + tid * 16;
    int row = o / ROWBYTES;
    int blk = (o >> 4) & MASK;
    int sb  = blk ^ (row & MASK & 7);
    const char* src = g + (size_t)row * strideBytes + (sb << 4);
    __builtin_amdgcn_global_load_lds((GV*)src, (LV*)(lds + o), 16, 0, 0);
  }
}

template<int ROWBYTES>
DEVFN short8 frag_ld(const char* lds, int row, int kbyte) {
  constexpr int MASK = (ROWBYTES >> 4) - 1;
  int blk = kbyte >> 4;
  int sb  = blk ^ (row & MASK & 7);
  return *(const short8*)(lds + row * ROWBYTES + (sb << 4));
}

DEVFN f32x4 mfma16(short8 a, short8 b, f32x4 c) {
  return __builtin_amdgcn_mfma_f32_16x16x32_bf16(a, b, c, 0, 0, 0);
}

// ---------------- merged prep kernels ----------------

__global__ void cvt3_kernel(const float* __restrict__ q, const float* __restrict__ k,
                            const float* __restrict__ v,
                            unsigned short* __restrict__ Xq,
                            unsigned short* __restrict__ Xk,
                            unsigned short* __restrict__ Xv, int n4) {
  int i = blockIdx.x * blockDim.x + threadIdx.x;
  if (i >= n4) return;
  const float* in = blockIdx.y == 0 ? q : (blockIdx.y == 1 ? k : v);
  unsigned short* out = blockIdx.y == 0 ? Xq : (blockIdx.y == 1 ? Xk : Xv);
  float4 val = ((const float4*)in)[i];
  ushort4 o;
  o.x = f32_bf16(val.x); o.y = f32_bf16(val.y);
  o.z = f32_bf16(val.z); o.w = f32_bf16(val.w);
  ((ushort4*)out)[i] = o;
}

// mask int32 {0,1} -> bf16 keep {1.0, 0.0}
__global__ void mask_prep_kernel(const int* __restrict__ m,
                                 unsigned short* __restrict__ ms, int n4) {
  int i = blockIdx.x * blockDim.x + threadIdx.x;
  if (i < n4) {
    int4 v = ((const int4*)m)[i];
    ushort4 o;
    o.x = v.x ? 0 : 0x3f80; o.y = v.y ? 0 : 0x3f80;
    o.z = v.z ? 0 : 0x3f80; o.w = v.w ? 0 : 0x3f80;
    ((ushort4*)ms)[i] = o;
  }
}

// all weight transposes in one launch: z 0-7 Wq, 8-15 Wk, 16-23 Wv, 24 Wo
__global__ void transpose_wall_kernel(const float* __restrict__ Wq,
                                      const float* __restrict__ Wk,
                                      const float* __restrict__ Wv,
                                      const float* __restrict__ Wo,
                                      unsigned short* __restrict__ WqT,
                                      unsigned short* __restrict__ WkT,
                                      unsigned short* __restrict__ WvT,
                                      unsigned short* __restrict__ WoT) {
  __shared__ float t[32][33];
  int z = blockIdx.z;
  const float* ip; unsigned short* op; int R, C;
  if (z < 8)       { ip = Wq + (size_t)z * Dd * Dd;        op = WqT + (size_t)z * Dd * Dd;        R = Dd; C = Dd; }
  else if (z < 16) { ip = Wk + (size_t)(z - 8) * Dd * Dd;  op = WkT + (size_t)(z - 8) * Dd * Dd;  R = Dd; C = Dd; }
  else if (z < 24) { ip = Wv + (size_t)(z - 16) * Dd * DVv; op = WvT + (size_t)(z - 16) * Dd * DVv; R = Dd; C = DVv; }
  else             { ip = Wo; op = WoT; R = Hh * DVv; C = DOo; }
  int c0 = blockIdx.x * 32, r0 = blockIdx.y * 32;
  if (c0 >= C || r0 >= R) return;
#pragma unroll
  for (int i = threadIdx.y; i < 32; i += 8)
    t[i][threadIdx.x] = ip[(size_t)(r0 + i) * C + c0 + threadIdx.x];
  __syncthreads();
#pragma unroll
  for (int i = threadIdx.y; i < 32; i += 8)
    op[(size_t)(c0 + i) * R + r0 + threadIdx.x] = f32_bf16(t[threadIdx.x][i]);
}

// in: [G][R][C] bf16 -> out: [G][C][R] bf16
__global__ void transpose_u16_kernel(const unsigned short* __restrict__ in,
                                     unsigned short* __restrict__ out, int R, int C) {
  __shared__ unsigned short t[32][33];
  int g = blockIdx.z;
  int c0 = blockIdx.x * 32, r0 = blockIdx.y * 32;
  const unsigned short* ip = in + (size_t)g * R * C;
  unsigned short* op = out + (size_t)g * R * C;
#pragma unroll
  for (int i = threadIdx.y; i < 32; i += 8)
    t[i][threadIdx.x] = ip[(size_t)(r0 + i) * C + c0 + threadIdx.x];
  __syncthreads();
#pragma unroll
  for (int i = threadIdx.y; i < 32; i += 8)
    op[(size_t)(c0 + i) * R + r0 + threadIdx.x] = t[threadIdx.x][i];
}

// ---------------- NT GEMM 128-tile (projections + Wo) ----------------

template<int NCG, bool OUTF32>
__global__ __launch_bounds__(256)
void gemm_nt_kernel(const unsigned short* __restrict__ A,
                    const unsigned short* __restrict__ BtAll,
                    void* __restrict__ Cb, int HeadsOut, int Ncols) {
  constexpr int BN = NCG * 32;
  constexpr int NL = 4 + BN / 32;
  __shared__ alignas(16) char As[2][16384];
  __shared__ alignas(16) char Bs[2][BN * 128];
  int tid = threadIdx.x, lane = tid & 63;
  int w = tid >> 6, wr = w >> 1, wc = w & 1;
  int tM = blockIdx.x, tN = blockIdx.y, h = blockIdx.z;
  const char* Ab  = (const char*)A + ((size_t)tM * 128) * 1024;
  const char* Btb = (const char*)BtAll + ((size_t)h * Ncols + tN * BN) * 1024;

  f32x4 acc[4][NCG] = {};

  stage_tile<128, 16384>(Ab, 1024, As[0], tid);
  stage_tile<128, BN * 128>(Btb, 1024, Bs[0], tid);
#pragma unroll
  for (int kk = 0; kk < 8; ++kk) {
    int cur = kk & 1;
    if (kk < 7) {
      stage_tile<128, 16384>(Ab + (kk + 1) * 128, 1024, As[cur ^ 1], tid);
      stage_tile<128, BN * 128>(Btb + (kk + 1) * 128, 1024, Bs[cur ^ 1], tid);
      wait_vmcnt<NL == 8 ? 8 : 6>();
    } else {
      wait_vmcnt<0>();
    }
    barrier_raw();
#pragma unroll
    for (int c = 0; c < 2; ++c) {
      short8 af[4], bf[NCG];
#pragma unroll
      for (int rg = 0; rg < 4; ++rg)
        af[rg] = frag_ld<128>(As[cur], wr * 64 + rg * 16 + (lane & 15),
                              c * 64 + (lane >> 4) * 16);
#pragma unroll
      for (int cg = 0; cg < NCG; ++cg)
        bf[cg] = frag_ld<128>(Bs[cur], wc * (NCG * 16) + cg * 16 + (lane & 15),
                              c * 64 + (lane >> 4) * 16);
#pragma unroll
      for (int rg = 0; rg < 4; ++rg)
#pragma unroll
        for (int cg = 0; cg < NCG; ++cg)
          acc[rg][cg] = mfma16(af[rg], bf[cg], acc[rg][cg]);
    }
    barrier_raw();
  }

#pragma unroll
  for (int rg = 0; rg < 4; ++rg)
#pragma unroll
    for (int cg = 0; cg < NCG; ++cg)
#pragma unroll
      for (int r = 0; r < 4; ++r) {
        int grow = tM * 128 + wr * 64 + rg * 16 + (lane >> 4) * 4 + r;
        int col  = tN * BN + wc * (NCG * 16) + cg * 16 + (lane & 15);
        size_t orow = ((size_t)(grow >> 11) * HeadsOut + h) * 2048 + (grow & 2047);
        if constexpr (OUTF32)
          ((float*)Cb)[orow * Ncols + col] = acc[rg][cg][r];
        else
          ((unsigned short*)Cb)[orow * Ncols + col] = f32_bf16(acc[rg][cg][r]);
      }
}

// ---------------- fused S=QK^T (mask+scale -> attn f32) + O=S*V ----------------
// Block = (bh, 64 Q-rows); 1024 blocks; 4 waves; LDS 80 KB -> 2 blocks/CU.
// Per j (16 tiles of 128 K-rows): 2-phase k-loop (8 steps, BK=64) computes
// S[64x128]; epilogue: mask*scale -> attn f32 store + bf16 pack into swizzled
// Ss; PV accumulates O[64x64] in regs. Vt prefetched at kk=5 (gate math:
// kk5 leaves S6+Vt=10, kk6 leaves S7=6 => Vt landed before kk6's barrier).

__global__ __launch_bounds__(256)
void attn2_kernel(const unsigned short* __restrict__ Qb,
                  const unsigned short* __restrict__ Kb,
                  const unsigned short* __restrict__ VbT,
                  const unsigned short* __restrict__ ms,
                  float* __restrict__ attn_out,
                  unsigned short* __restrict__ QKV) {
  __shared__ alignas(16) char Qs[2][8192];    // 64 x 64 bf16
  __shared__ alignas(16) char Ks[2][16384];   // 128 x 64 bf16
  __shared__ alignas(16) char Ss[16384];      // 64 x 128 bf16 (swizzled)
  __shared__ alignas(16) char Vt[16384];      // 64 x 128 bf16 (V^T tile)
  int tid = threadIdx.x, lane = tid & 63;
  int wv = tid >> 6;
  int fid = blockIdx.x;
  int orig = (fid & 7) * 128 + (fid >> 3);    // XCD chunk: 4 bh per XCD
  int bh = orig >> 5, tM = orig & 31;
  int b = bh >> 3, h = bh & 7;

  const char* Qg  = (const char*)Qb + ((size_t)bh * Nn + tM * 64) * 1024;
  const char* Kg0 = (const char*)Kb + (size_t)bh * Nn * 1024;
  const char* Vg0 = (const char*)VbT + (size_t)bh * DVv * Nn * 2;
  const float scale = 0.044194173824159216f;  // 1/sqrt(512)

  f32x4 oacc[4] = {};

  // prologue for j=0
  stage_tile<128, 8192>(Qg, 1024, Qs[0], tid);
  stage_tile<128, 16384>(Kg0, 1024, Ks[0], tid);

#pragma unroll 1
  for (int j = 0; j < 16; ++j) {
    const char* Kg = Kg0 + (size_t)j * 128 * 1024;
    f32x4 acc[4][2] = {};

#pragma unroll
    for (int kk = 0; kk < 8; ++kk) {
      int cur = kk & 1;
      if (kk < 7) {
        stage_tile<128, 8192>(Qg + (kk + 1) * 128, 1024, Qs[cur ^ 1], tid);
        stage_tile<128, 16384>(Kg + (kk + 1) * 128, 1024, Ks[cur ^ 1], tid);
        if (kk == 5) stage_tile<256, 16384>(Vg0 + j * 256, Nn * 2, Vt, tid);
      }
      if (kk == 5)      wait_vmcnt<10>();
      else if (kk < 7)  wait_vmcnt<6>();
      else              wait_vmcnt<0>();
      barrier_raw();
#pragma unroll
      for (int c = 0; c < 2; ++c) {
        short8 af[4], bf[2];
#pragma unroll
        for (int rg = 0; rg < 4; ++rg)
          af[rg] = frag_ld<128>(Qs[cur], rg * 16 + (lane & 15),
                                c * 64 + (lane >> 4) * 16);
#pragma unroll
        for (int cg = 0; cg < 2; ++cg)
          bf[cg] = frag_ld<128>(Ks[cur], wv * 32 + cg * 16 + (lane & 15),
                                c * 64 + (lane >> 4) * 16);
#pragma unroll
        for (int rg = 0; rg < 4; ++rg)
#pragma unroll
          for (int cg = 0; cg < 2; ++cg)
            acc[rg][cg] = mfma16(af[rg], bf[cg], acc[rg][cg]);
      }
      barrier_raw();
    }

    // epilogue: mask*scale -> attn store (f32) + Ss pack (bf16, swizzled)
    float* attn_tile = attn_out + (((size_t)bh * Nn + tM * 64) * Nn) + j * 128;
    const unsigned short* mrow0 = ms + (size_t)(tM * 64) * Nn + j * 128;
#pragma unroll
    for (int rg = 0; rg < 4; ++rg)
#pragma unroll
      for (int cg = 0; cg < 2; ++cg)
#pragma unroll
        for (int r = 0; r < 4; ++r) {
          int q  = rg * 16 + (lane >> 4) * 4 + r;
          int kc = wv * 32 + cg * 16 + (lane & 15);
          unsigned short kv = mrow0[(size_t)q * Nn + kc];
          float keep = __builtin_bit_cast(float, (unsigned)kv << 16);
          float vvf = acc[rg][cg][r] * scale * keep;
          attn_tile[(size_t)q * Nn + kc] = vvf;
          int baddr = q * 256 + (((kc >> 3) ^ (q & 7)) << 4) + (kc & 7) * 2;
          *(unsigned short*)(Ss + baddr) = f32_bf16(vvf);
        }
    wait_lgkm0();
    barrier_raw();

    // PV: O[64x64] += Ss[64x128] * Vt[64x128]^T ; wave owns v-cols wv*16..+15
#pragma unroll
    for (int ks = 0; ks < 4; ++ks) {
      short8 a2[4], b2;
#pragma unroll
      for (int rg = 0; rg < 4; ++rg)
        a2[rg] = frag_ld<256>(Ss, rg * 16 + (lane & 15),
                              ks * 64 + (lane >> 4) * 16);
      b2 = frag_ld<256>(Vt, wv * 16 + (lane & 15), ks * 64 + (lane >> 4) * 16);
#pragma unroll
      for (int rg = 0; rg < 4; ++rg)
        oacc[rg] = mfma16(a2[rg], b2, oacc[rg]);
    }

    // prefetch next j's first k-chunk (slot 0 free: last read at kk=6,
    // separated by kk=7's barriers + epilogue barrier)
    if (j < 15) {
      stage_tile<128, 8192>(Qg, 1024, Qs[0], tid);
      stage_tile<128, 16384>(Kg0 + (size_t)(j + 1) * 128 * 1024, 1024, Ks[0], tid);
    }
  }

  // write O -> QKV[b][n][h*64+v] bf16
#pragma unroll
  for (int rg = 0; rg < 4; ++rg)
#pragma unroll
    for (int r = 0; r < 4; ++r) {
      int q = rg * 16 + (lane >> 4) * 4 + r;
      int vcol = wv * 16 + (lane & 15);
      QKV[((size_t)b * Nn + tM * 64 + q) * (Hh * DVv) + h * DVv + vcol] =
          f32_bf16(oacc[rg][r]);
    }
}

// ---------------- host ----------------

extern "C" void kernel_launch(void* const* d_in, const int* in_sizes, int n_in,
                              void* d_out, int out_size, void* d_ws, size_t ws_size,
                              hipStream_t stream) {
  const float* q    = (const float*)d_in[0];
  const float* k    = (const float*)d_in[1];
  const float* v    = (const float*)d_in[2];
  const int*   mask = (const int*)d_in[3];
  const float* Wq   = (const float*)d_in[4];
  const float* Wk   = (const float*)d_in[5];
  const float* Wv   = (const float*)d_in[6];
  const float* Wo   = (const float*)d_in[7];

  char* ws = (char*)d_ws;
  size_t off = 0;
  auto alloc = [&](size_t bytes) {
    char* p = ws + off;
    off += (bytes + 255) & ~(size_t)255;
    return p;
  };
  unsigned short* WqT  = (unsigned short*)alloc((size_t)Hh * Dd * Dd * 2);
  unsigned short* WkT  = (unsigned short*)alloc((size_t)Hh * Dd * Dd * 2);
  unsigned short* WvT  = (unsigned short*)alloc((size_t)Hh * DVv * Dd * 2);
  unsigned short* WoT  = (unsigned short*)alloc((size_t)DOo * Hh * DVv * 2);
  unsigned short* Xq   = (unsigned short*)alloc((size_t)Bb * Nn * Dd * 2);
  unsigned short* Xk   = (unsigned short*)alloc((size_t)Bb * Nn * Dd * 2);
  unsigned short* Xv   = (unsigned short*)alloc((size_t)Bb * Nn * Dd * 2);
  unsigned short* Qb   = (unsigned short*)alloc((size_t)Bb * Hh * Nn * Dd * 2);
  unsigned short* Kb   = (unsigned short*)alloc((size_t)Bb * Hh * Nn * Dd * 2);
  unsigned short* Vb   = (unsigned short*)alloc((size_t)Bb * Hh * Nn * DVv * 2);
  unsigned short* VbT  = (unsigned short*)alloc((size_t)Bb * Hh * DVv * Nn * 2);
  unsigned short* QKVb = (unsigned short*)alloc((size_t)Bb * Nn * Hh * DVv * 2);
  unsigned short* Ms   = (unsigned short*)alloc((size_t)Nn * Nn * 2);

  int n4 = Bb * Nn * Dd / 4;
  cvt3_kernel<<<dim3(n4 / 256, 3), dim3(256), 0, stream>>>(q, k, v, Xq, Xk, Xv, n4);
  mask_prep_kernel<<<dim3(Nn * Nn / 4 / 256), dim3(256), 0, stream>>>(mask, Ms, Nn * Nn / 4);
  transpose_wall_kernel<<<dim3(16, 16, 25), dim3(32, 8), 0, stream>>>(
      Wq, Wk, Wv, Wo, WqT, WkT, WvT, WoT);

  gemm_nt_kernel<4, false><<<dim3(64, 4, Hh), dim3(256), 0, stream>>>(Xq, WqT, Qb, Hh, Dd);
  gemm_nt_kernel<4, false><<<dim3(64, 4, Hh), dim3(256), 0, stream>>>(Xk, WkT, Kb, Hh, Dd);
  gemm_nt_kernel<2, false><<<dim3(64, 1, Hh), dim3(256), 0, stream>>>(Xv, WvT, Vb, Hh, DVv);

  transpose_u16_kernel<<<dim3(DVv / 32, Nn / 32, Bb * Hh), dim3(32, 8), 0, stream>>>(Vb, VbT, Nn, DVv);

  float* outp  = (float*)d_out;
  float* attnp = outp + (size_t)Bb * Nn * DOo;

  attn2_kernel<<<dim3(1024), dim3(256), 0, stream>>>(Qb, Kb, VbT, Ms, attnp, QKVb);

  gemm_nt_kernel<4, true><<<dim3(64, 4, 1), dim3(256), 0, stream>>>(QKVb, WoT, outp, 1, DOo);

  (void)in_sizes; (void)n_in; (void)out_size; (void)ws_size;
}

// Round 6
// 802.154 us; speedup vs baseline: 1.2065x; 1.2065x over previous
//
#include <hip/hip_runtime.h>
#include <hip/hip_bf16.h>

#define DEVFN __device__ __forceinline__

constexpr int Bb = 4, Nn = 2048, Dd = 512, Hh = 8, DVv = 64, DOo = 512;

typedef short short8 __attribute__((ext_vector_type(8)));
typedef float f32x4 __attribute__((ext_vector_type(4)));

typedef __attribute__((address_space(1))) void GV;   // global
typedef __attribute__((address_space(3))) void LV;   // LDS

DEVFN unsigned short f32_bf16(float f) {
  unsigned u = __builtin_bit_cast(unsigned, f);
  u += 0x7fffu + ((u >> 16) & 1u);          // RNE
  return (unsigned short)(u >> 16);
}

DEVFN void barrier_raw() {
  asm volatile("" ::: "memory");
  __builtin_amdgcn_s_barrier();
  asm volatile("" ::: "memory");
}

template<int Nv> DEVFN void wait_vmcnt() {
  if constexpr (Nv == 0)      asm volatile("s_waitcnt vmcnt(0)"  ::: "memory");
  else if constexpr (Nv == 6) asm volatile("s_waitcnt vmcnt(6)"  ::: "memory");
  else if constexpr (Nv == 8) asm volatile("s_waitcnt vmcnt(8)"  ::: "memory");
  else static_assert(Nv == 0 || Nv == 6 || Nv == 8, "bad vmcnt");
}
DEVFN void wait_lgkm0() { asm volatile("s_waitcnt lgkmcnt(0)" ::: "memory"); }

// Stage TOTAL bytes into LDS. Linear LDS dest (required by global_load_lds),
// XOR-swizzled GLOBAL source so a swizzled ds_read is conflict-free:
// LDS(row,blk) holds global(row, blk ^ (row & min(nblk-1,7))).
template<int ROWBYTES, int TOTAL, int NTHR = 256>
DEVFN void stage_tile(const char* g, int strideBytes, char* lds, int tid) {
  constexpr int MASK = (ROWBYTES >> 4) - 1;
#pragma unroll
  for (int off = 0; off < TOTAL; off += NTHR * 16) {
    int o   = off + tid * 16;
    int row = o / ROWBYTES;
    int blk = (o >> 4) & MASK;
    int sb  = blk ^ (row & MASK & 7);
    const char* src = g + (size_t)row * strideBytes + (sb << 4);
    __builtin_amdgcn_global_load_lds((GV*)src, (LV*)(lds + o), 16, 0, 0);
  }
}

template<int ROWBYTES>
DEVFN short8 frag_ld(const char* lds, int row, int kbyte) {
  constexpr int MASK = (ROWBYTES >> 4) - 1;
  int blk = kbyte >> 4;
  int sb  = blk ^ (row & MASK & 7);
  return *(const short8*)(lds + row * ROWBYTES + (sb << 4));
}

DEVFN f32x4 mfma16(short8 a, short8 b, f32x4 c) {
  return __builtin_amdgcn_mfma_f32_16x16x32_bf16(a, b, c, 0, 0, 0);
}

// ---------------- merged prep kernels ----------------

__global__ void cvt3_kernel(const float* __restrict__ q, const float* __restrict__ k,
                            const float* __restrict__ v,
                            unsigned short* __restrict__ Xq,
                            unsigned short* __restrict__ Xk,
                            unsigned short* __restrict__ Xv, int n4) {
  int i = blockIdx.x * blockDim.x + threadIdx.x;
  if (i >= n4) return;
  const float* in = blockIdx.y == 0 ? q : (blockIdx.y == 1 ? k : v);
  unsigned short* out = blockIdx.y == 0 ? Xq : (blockIdx.y == 1 ? Xk : Xv);
  float4 val = ((const float4*)in)[i];
  ushort4 o;
  o.x = f32_bf16(val.x); o.y = f32_bf16(val.y);
  o.z = f32_bf16(val.z); o.w = f32_bf16(val.w);
  ((ushort4*)out)[i] = o;
}

// mask int32 {0,1} -> bf16 keep {1.0, 0.0}
__global__ void mask_prep_kernel(const int* __restrict__ m,
                                 unsigned short* __restrict__ ms, int n4) {
  int i = blockIdx.x * blockDim.x + threadIdx.x;
  if (i < n4) {
    int4 v = ((const int4*)m)[i];
    ushort4 o;
    o.x = v.x ? 0 : 0x3f80; o.y = v.y ? 0 : 0x3f80;
    o.z = v.z ? 0 : 0x3f80; o.w = v.w ? 0 : 0x3f80;
    ((ushort4*)ms)[i] = o;
  }
}

// all weight transposes in one launch: z 0-7 Wq, 8-15 Wk, 16-23 Wv, 24 Wo
__global__ void transpose_wall_kernel(const float* __restrict__ Wq,
                                      const float* __restrict__ Wk,
                                      const float* __restrict__ Wv,
                                      const float* __restrict__ Wo,
                                      unsigned short* __restrict__ WqT,
                                      unsigned short* __restrict__ WkT,
                                      unsigned short* __restrict__ WvT,
                                      unsigned short* __restrict__ WoT) {
  __shared__ float t[32][33];
  int z = blockIdx.z;
  const float* ip; unsigned short* op; int R, C;
  if (z < 8)       { ip = Wq + (size_t)z * Dd * Dd;        op = WqT + (size_t)z * Dd * Dd;        R = Dd; C = Dd; }
  else if (z < 16) { ip = Wk + (size_t)(z - 8) * Dd * Dd;  op = WkT + (size_t)(z - 8) * Dd * Dd;  R = Dd; C = Dd; }
  else if (z < 24) { ip = Wv + (size_t)(z - 16) * Dd * DVv; op = WvT + (size_t)(z - 16) * Dd * DVv; R = Dd; C = DVv; }
  else             { ip = Wo; op = WoT; R = Hh * DVv; C = DOo; }
  int c0 = blockIdx.x * 32, r0 = blockIdx.y * 32;
  if (c0 >= C || r0 >= R) return;
#pragma unroll
  for (int i = threadIdx.y; i < 32; i += 8)
    t[i][threadIdx.x] = ip[(size_t)(r0 + i) * C + c0 + threadIdx.x];
  __syncthreads();
#pragma unroll
  for (int i = threadIdx.y; i < 32; i += 8)
    op[(size_t)(c0 + i) * R + r0 + threadIdx.x] = f32_bf16(t[threadIdx.x][i]);
}

// ---------------- NT GEMM 128-tile ----------------
// EPI 0: bf16 out, head-strided rows. EPI 1: f32 out. EPI 2: bf16 out
// transposed to [b*Hh+h][col][n] (direct-VbT for the V projection).

template<int NCG, int EPI>
__global__ __launch_bounds__(256)
void gemm_nt_kernel(const unsigned short* __restrict__ A,
                    const unsigned short* __restrict__ BtAll,
                    void* __restrict__ Cb, int HeadsOut, int Ncols) {
  constexpr int BN = NCG * 32;
  constexpr int NL = 4 + BN / 32;
  __shared__ alignas(16) char As[2][16384];
  __shared__ alignas(16) char Bs[2][BN * 128];
  int tid = threadIdx.x, lane = tid & 63;
  int w = tid >> 6, wr = w >> 1, wc = w & 1;
  int tM = blockIdx.x, tN = blockIdx.y, h = blockIdx.z;
  const char* Ab  = (const char*)A + ((size_t)tM * 128) * 1024;
  const char* Btb = (const char*)BtAll + ((size_t)h * Ncols + tN * BN) * 1024;

  f32x4 acc[4][NCG] = {};

  stage_tile<128, 16384>(Ab, 1024, As[0], tid);
  stage_tile<128, BN * 128>(Btb, 1024, Bs[0], tid);
#pragma unroll
  for (int kk = 0; kk < 8; ++kk) {
    int cur = kk & 1;
    if (kk < 7) {
      stage_tile<128, 16384>(Ab + (kk + 1) * 128, 1024, As[cur ^ 1], tid);
      stage_tile<128, BN * 128>(Btb + (kk + 1) * 128, 1024, Bs[cur ^ 1], tid);
      wait_vmcnt<NL == 8 ? 8 : 6>();
    } else {
      wait_vmcnt<0>();
    }
    barrier_raw();
#pragma unroll
    for (int c = 0; c < 2; ++c) {
      short8 af[4], bf[NCG];
#pragma unroll
      for (int rg = 0; rg < 4; ++rg)
        af[rg] = frag_ld<128>(As[cur], wr * 64 + rg * 16 + (lane & 15),
                              c * 64 + (lane >> 4) * 16);
#pragma unroll
      for (int cg = 0; cg < NCG; ++cg)
        bf[cg] = frag_ld<128>(Bs[cur], wc * (NCG * 16) + cg * 16 + (lane & 15),
                              c * 64 + (lane >> 4) * 16);
#pragma unroll
      for (int rg = 0; rg < 4; ++rg)
#pragma unroll
        for (int cg = 0; cg < NCG; ++cg)
          acc[rg][cg] = mfma16(af[rg], bf[cg], acc[rg][cg]);
    }
    barrier_raw();
  }

#pragma unroll
  for (int rg = 0; rg < 4; ++rg)
#pragma unroll
    for (int cg = 0; cg < NCG; ++cg) {
      if constexpr (EPI == 2) {
        int grow0 = tM * 128 + wr * 64 + rg * 16 + (lane >> 4) * 4;
        int col   = tN * BN + wc * (NCG * 16) + cg * 16 + (lane & 15);
        int bq = grow0 >> 11, n0 = grow0 & 2047;
        ushort4 o;
        o.x = f32_bf16(acc[rg][cg][0]); o.y = f32_bf16(acc[rg][cg][1]);
        o.z = f32_bf16(acc[rg][cg][2]); o.w = f32_bf16(acc[rg][cg][3]);
        *(ushort4*)&((unsigned short*)Cb)[
            (((size_t)bq * Hh + h) * DVv + col) * 2048 + n0] = o;
      } else {
#pragma unroll
        for (int r = 0; r < 4; ++r) {
          int grow = tM * 128 + wr * 64 + rg * 16 + (lane >> 4) * 4 + r;
          int col  = tN * BN + wc * (NCG * 16) + cg * 16 + (lane & 15);
          size_t orow = ((size_t)(grow >> 11) * HeadsOut + h) * 2048 + (grow & 2047);
          if constexpr (EPI == 1)
            ((float*)Cb)[orow * Ncols + col] = acc[rg][cg][r];
          else
            ((unsigned short*)Cb)[orow * Ncols + col] = f32_bf16(acc[rg][cg][r]);
        }
      }
    }
}

// ---------------- S = Q*K^T + mask + scale -> attn f32 (+ optional bf16 S) ----
// One block per 128x128 S-tile. 8192 blocks, XCD-chunked swizzle.

__global__ __launch_bounds__(256)
void qk_attn_kernel(const unsigned short* __restrict__ Qb,
                    const unsigned short* __restrict__ Kb,
                    const unsigned short* __restrict__ ms,
                    float* __restrict__ attn_out,
                    unsigned short* __restrict__ Sbf) {
  __shared__ alignas(16) char As[2][16384];
  __shared__ alignas(16) char Bs[2][16384];
  int tid = threadIdx.x, lane = tid & 63;
  int w = tid >> 6, wr = w >> 1, wc = w & 1;
  int fid = blockIdx.x;
  int orig = (fid & 7) * 1024 + (fid >> 3);     // XCD-chunked (8192 % 8 == 0)
  int tM = orig & 15, tN = (orig >> 4) & 15, bh = orig >> 8;

  const char* Ab  = (const char*)Qb + ((size_t)bh * Nn + tM * 128) * 1024;
  const char* Btb = (const char*)Kb + ((size_t)bh * Nn + tN * 128) * 1024;
  const float scale = 0.044194173824159216f;   // 1/sqrt(512)

  f32x4 acc[4][4] = {};

  stage_tile<128, 16384>(Ab, 1024, As[0], tid);
  stage_tile<128, 16384>(Btb, 1024, Bs[0], tid);
#pragma unroll
  for (int kk = 0; kk < 8; ++kk) {
    int cur = kk & 1;
    if (kk < 7) {
      stage_tile<128, 16384>(Ab + (kk + 1) * 128, 1024, As[cur ^ 1], tid);
      stage_tile<128, 16384>(Btb + (kk + 1) * 128, 1024, Bs[cur ^ 1], tid);
      wait_vmcnt<8>();
    } else {
      wait_vmcnt<0>();
    }
    barrier_raw();
#pragma unroll
    for (int c = 0; c < 2; ++c) {
      short8 af[4], bf[4];
#pragma unroll
      for (int rg = 0; rg < 4; ++rg)
        af[rg] = frag_ld<128>(As[cur], wr * 64 + rg * 16 + (lane & 15),
                              c * 64 + (lane >> 4) * 16);
#pragma unroll
      for (int cg = 0; cg < 4; ++cg)
        bf[cg] = frag_ld<128>(Bs[cur], wc * 64 + cg * 16 + (lane & 15),
                              c * 64 + (lane >> 4) * 16);
#pragma unroll
      for (int rg = 0; rg < 4; ++rg)
#pragma unroll
        for (int cg = 0; cg < 4; ++cg)
          acc[rg][cg] = mfma16(af[rg], bf[cg], acc[rg][cg]);
    }
    barrier_raw();
  }

  // epilogue: vv = acc * scale * keep ; write attn f32 (+ bf16 S for pv2)
#pragma unroll
  for (int rg = 0; rg < 4; ++rg)
#pragma unroll
    for (int cg = 0; cg < 4; ++cg)
#pragma unroll
      for (int r = 0; r < 4; ++r) {
        int rowL = wr * 64 + rg * 16 + (lane >> 4) * 4 + r;
        int colL = wc * 64 + cg * 16 + (lane & 15);
        int qrow = tM * 128 + rowL, kcol = tN * 128 + colL;
        unsigned short kv = ms[(size_t)qrow * Nn + kcol];
        float keep = __builtin_bit_cast(float, (unsigned)kv << 16);
        float vv = acc[rg][cg][r] * scale * keep;
        size_t idx = ((size_t)bh * Nn + qrow) * Nn + kcol;
        attn_out[idx] = vv;
        if (Sbf) Sbf[idx] = f32_bf16(vv);
      }
}

// ---------------- pv2: O = Sbf16 * VbT^T, proven gemm_nt structure ----------
// Per (tM, bh): C[128 x 64] = S[128 x 2048] * VbT[64 x 2048]^T. BK=64,
// 32 k-steps, counted vmcnt(6), LDS 48 KB -> 3 blocks/CU.

__global__ __launch_bounds__(256)
void pv2_kernel(const unsigned short* __restrict__ Sb,
                const unsigned short* __restrict__ VbT,
                unsigned short* __restrict__ QKV) {
  __shared__ alignas(16) char As[2][16384];   // 128 x 64 bf16
  __shared__ alignas(16) char Bs[2][8192];    // 64 x 64 bf16
  int tid = threadIdx.x, lane = tid & 63;
  int w = tid >> 6, wr = w >> 1, wc = w & 1;
  int tM = blockIdx.x, bh = blockIdx.y;
  int b = bh >> 3, h = bh & 7;
  const char* Ab  = (const char*)Sb + ((size_t)bh * Nn + tM * 128) * (Nn * 2);
  const char* Btb = (const char*)VbT + (size_t)bh * DVv * Nn * 2;

  f32x4 acc[4][2] = {};

  stage_tile<128, 16384>(Ab, Nn * 2, As[0], tid);
  stage_tile<128, 8192>(Btb, Nn * 2, Bs[0], tid);
#pragma unroll 2
  for (int kk = 0; kk < 32; ++kk) {
    int cur = kk & 1;
    if (kk < 31) {
      stage_tile<128, 16384>(Ab + (kk + 1) * 128, Nn * 2, As[cur ^ 1], tid);
      stage_tile<128, 8192>(Btb + (kk + 1) * 128, Nn * 2, Bs[cur ^ 1], tid);
      wait_vmcnt<6>();
    } else {
      wait_vmcnt<0>();
    }
    barrier_raw();
#pragma unroll
    for (int c = 0; c < 2; ++c) {
      short8 af[4], bf2[2];
#pragma unroll
      for (int rg = 0; rg < 4; ++rg)
        af[rg] = frag_ld<128>(As[cur], wr * 64 + rg * 16 + (lane & 15),
                              c * 64 + (lane >> 4) * 16);
#pragma unroll
      for (int cg = 0; cg < 2; ++cg)
        bf2[cg] = frag_ld<128>(Bs[cur], wc * 32 + cg * 16 + (lane & 15),
                               c * 64 + (lane >> 4) * 16);
#pragma unroll
      for (int rg = 0; rg < 4; ++rg)
#pragma unroll
        for (int cg = 0; cg < 2; ++cg)
          acc[rg][cg] = mfma16(af[rg], bf2[cg], acc[rg][cg]);
    }
    barrier_raw();
  }

#pragma unroll
  for (int rg = 0; rg < 4; ++rg)
#pragma unroll
    for (int cg = 0; cg < 2; ++cg)
#pragma unroll
      for (int r = 0; r < 4; ++r) {
        int rowL = wr * 64 + rg * 16 + (lane >> 4) * 4 + r;
        int colL = wc * 32 + cg * 16 + (lane & 15);
        size_t grow = (size_t)tM * 128 + rowL;
        QKV[((size_t)b * Nn + grow) * (Hh * DVv) + h * DVv + colL] =
            f32_bf16(acc[rg][cg][r]);
      }
}

// ---------------- pv fallback (f32 S from d_out), from R4 ----------------

__global__ __launch_bounds__(256)
void pv_kernel(const float* __restrict__ attn,
               const unsigned short* __restrict__ VbT,
               unsigned short* __restrict__ QKV) {
  __shared__ alignas(16) char As[2][8192];
  __shared__ alignas(16) char Bs[2][8192];
  int tid = threadIdx.x, lane = tid & 63;
  int w = tid >> 6, wr = w >> 1, wc = w & 1;
  int tM = blockIdx.x, bh = blockIdx.y;
  int b = bh >> 3, h = bh & 7;

  int arow = tid >> 2, aseg = tid & 3;
  const float* Ag = attn + ((size_t)bh * Nn + (size_t)tM * 64 + arow) * Nn
                    + aseg * 16;
  const char* Btb = (const char*)VbT + (size_t)bh * DVv * Nn * 2;

  f32x4 acc[2][2] = {};

  auto packA = [&](float4 ar[4], char* dst) {
    short8 s0, s1;
#pragma unroll
    for (int e = 0; e < 4; ++e) {
      s0[e]     = (short)f32_bf16(ar[0][e]);
      s0[e + 4] = (short)f32_bf16(ar[1][e]);
      s1[e]     = (short)f32_bf16(ar[2][e]);
      s1[e + 4] = (short)f32_bf16(ar[3][e]);
    }
    int b0 = (aseg * 2) ^ (arow & 7), b1 = (aseg * 2 + 1) ^ (arow & 7);
    *(short8*)(dst + arow * 128 + (b0 << 4)) = s0;
    *(short8*)(dst + arow * 128 + (b1 << 4)) = s1;
  };

  {
    float4 ar[4];
#pragma unroll
    for (int i = 0; i < 4; ++i) ar[i] = ((const float4*)Ag)[i];
    stage_tile<128, 8192>(Btb, Nn * 2, Bs[0], tid);
    wait_vmcnt<0>();
    packA(ar, As[0]);
    wait_lgkm0();
    barrier_raw();
  }

#pragma unroll 2
  for (int kk = 0; kk < 32; ++kk) {
    int cur = kk & 1;
    float4 ar[4];
    if (kk < 31) {
      const float* an = Ag + (kk + 1) * 64;
#pragma unroll
      for (int i = 0; i < 4; ++i) ar[i] = ((const float4*)an)[i];
      stage_tile<128, 8192>(Btb + (kk + 1) * 128, Nn * 2, Bs[cur ^ 1], tid);
    }
#pragma unroll
    for (int c = 0; c < 2; ++c) {
      short8 af[2], bf2[2];
#pragma unroll
      for (int rg = 0; rg < 2; ++rg)
        af[rg] = frag_ld<128>(As[cur], wr * 32 + rg * 16 + (lane & 15),
                              c * 64 + (lane >> 4) * 16);
#pragma unroll
      for (int cg = 0; cg < 2; ++cg)
        bf2[cg] = frag_ld<128>(Bs[cur], wc * 32 + cg * 16 + (lane & 15),
                               c * 64 + (lane >> 4) * 16);
#pragma unroll
      for (int rg = 0; rg < 2; ++rg)
#pragma unroll
        for (int cg = 0; cg < 2; ++cg)
          acc[rg][cg] = mfma16(af[rg], bf2[cg], acc[rg][cg]);
    }
    if (kk < 31) {
      wait_vmcnt<0>();
      packA(ar, As[cur ^ 1]);
      wait_lgkm0();
    }
    barrier_raw();
  }

#pragma unroll
  for (int rg = 0; rg < 2; ++rg)
#pragma unroll
    for (int cg = 0; cg < 2; ++cg)
#pragma unroll
      for (int r = 0; r < 4; ++r) {
        int rowL = wr * 32 + rg * 16 + (lane >> 4) * 4 + r;
        int colL = wc * 32 + cg * 16 + (lane & 15);
        size_t grow = (size_t)tM * 64 + rowL;
        QKV[((size_t)b * Nn + grow) * (Hh * DVv) + h * DVv + colL] =
            f32_bf16(acc[rg][cg][r]);
      }
}

// ---------------- host ----------------

extern "C" void kernel_launch(void* const* d_in, const int* in_sizes, int n_in,
                              void* d_out, int out_size, void* d_ws, size_t ws_size,
                              hipStream_t stream) {
  const float* q    = (const float*)d_in[0];
  const float* k    = (const float*)d_in[1];
  const float* v    = (const float*)d_in[2];
  const int*   mask = (const int*)d_in[3];
  const float* Wq   = (const float*)d_in[4];
  const float* Wk   = (const float*)d_in[5];
  const float* Wv   = (const float*)d_in[6];
  const float* Wo   = (const float*)d_in[7];

  char* ws = (char*)d_ws;
  size_t off = 0;
  auto alloc = [&](size_t bytes) {
    char* p = ws + off;
    off += (bytes + 255) & ~(size_t)255;
    return p;
  };
  unsigned short* WqT  = (unsigned short*)alloc((size_t)Hh * Dd * Dd * 2);
  unsigned short* WkT  = (unsigned short*)alloc((size_t)Hh * Dd * Dd * 2);
  unsigned short* WvT  = (unsigned short*)alloc((size_t)Hh * DVv * Dd * 2);
  unsigned short* WoT  = (unsigned short*)alloc((size_t)DOo * Hh * DVv * 2);
  unsigned short* Xq   = (unsigned short*)alloc((size_t)Bb * Nn * Dd * 2);
  unsigned short* Xk   = (unsigned short*)alloc((size_t)Bb * Nn * Dd * 2);
  unsigned short* Xv   = (unsigned short*)alloc((size_t)Bb * Nn * Dd * 2);
  unsigned short* Qb   = (unsigned short*)alloc((size_t)Bb * Hh * Nn * Dd * 2);
  unsigned short* Kb   = (unsigned short*)alloc((size_t)Bb * Hh * Nn * Dd * 2);
  unsigned short* VbT  = (unsigned short*)alloc((size_t)Bb * Hh * DVv * Nn * 2);
  unsigned short* QKVb = (unsigned short*)alloc((size_t)Bb * Nn * Hh * DVv * 2);
  unsigned short* Ms   = (unsigned short*)alloc((size_t)Nn * Nn * 2);
  size_t sbf_bytes = (size_t)Bb * Hh * Nn * Nn * 2;
  bool use_sbf = (off + sbf_bytes) <= ws_size;
  unsigned short* Sbf = use_sbf ? (unsigned short*)alloc(sbf_bytes) : nullptr;

  int n4 = Bb * Nn * Dd / 4;
  cvt3_kernel<<<dim3(n4 / 256, 3), dim3(256), 0, stream>>>(q, k, v, Xq, Xk, Xv, n4);
  mask_prep_kernel<<<dim3(Nn * Nn / 4 / 256), dim3(256), 0, stream>>>(mask, Ms, Nn * Nn / 4);
  transpose_wall_kernel<<<dim3(16, 16, 25), dim3(32, 8), 0, stream>>>(
      Wq, Wk, Wv, Wo, WqT, WkT, WvT, WoT);

  gemm_nt_kernel<4, 0><<<dim3(64, 4, Hh), dim3(256), 0, stream>>>(Xq, WqT, Qb, Hh, Dd);
  gemm_nt_kernel<4, 0><<<dim3(64, 4, Hh), dim3(256), 0, stream>>>(Xk, WkT, Kb, Hh, Dd);
  gemm_nt_kernel<2, 2><<<dim3(64, 1, Hh), dim3(256), 0, stream>>>(Xv, WvT, VbT, Hh, DVv);

  float* outp  = (float*)d_out;
  float* attnp = outp + (size_t)Bb * Nn * DOo;

  qk_attn_kernel<<<dim3(8192), dim3(256), 0, stream>>>(Qb, Kb, Ms, attnp, Sbf);

  if (use_sbf)
    pv2_kernel<<<dim3(16, 32), dim3(256), 0, stream>>>(Sbf, VbT, QKVb);
  else
    pv_kernel<<<dim3(32, 32), dim3(256), 0, stream>>>(attnp, VbT, QKVb);

  gemm_nt_kernel<4, 1><<<dim3(64, 4, 1), dim3(256), 0, stream>>>(QKVb, WoT, outp, 1, DOo);

  (void)in_sizes; (void)n_in; (void)out_size;
}

// Round 8
// 555.935 us; speedup vs baseline: 1.7409x; 1.4429x over previous
//
#include <hip/hip_runtime.h>
#include <hip/hip_bf16.h>

#define DEVFN __device__ __forceinline__

constexpr int Bb = 4, Nn = 2048, Dd = 512, Hh = 8, DVv = 64, DOo = 512;

typedef short short8 __attribute__((ext_vector_type(8)));
typedef float f32x4 __attribute__((ext_vector_type(4)));

typedef __attribute__((address_space(1))) void GV;   // global
typedef __attribute__((address_space(3))) void LV;   // LDS

DEVFN unsigned short f32_bf16(float f) {
  unsigned u = __builtin_bit_cast(unsigned, f);
  u += 0x7fffu + ((u >> 16) & 1u);          // RNE
  return (unsigned short)(u >> 16);
}

DEVFN void barrier_raw() {
  asm volatile("" ::: "memory");
  __builtin_amdgcn_s_barrier();
  asm volatile("" ::: "memory");
}

template<int Nv> DEVFN void wait_vmcnt() {
  if constexpr (Nv == 0)      asm volatile("s_waitcnt vmcnt(0)"  ::: "memory");
  else if constexpr (Nv == 6) asm volatile("s_waitcnt vmcnt(6)"  ::: "memory");
  else if constexpr (Nv == 8) asm volatile("s_waitcnt vmcnt(8)"  ::: "memory");
  else static_assert(Nv == 0 || Nv == 6 || Nv == 8, "bad vmcnt");
}

// Stage TOTAL bytes into LDS. Linear LDS dest (required by global_load_lds),
// XOR-swizzled GLOBAL source so a swizzled ds_read is conflict-free:
// LDS(row,blk) holds global(row, blk ^ (row & min(nblk-1,7))).
template<int ROWBYTES, int TOTAL, int NTHR = 256>
DEVFN void stage_tile(const char* g, int strideBytes, char* lds, int tid) {
  constexpr int MASK = (ROWBYTES >> 4) - 1;
#pragma unroll
  for (int off = 0; off < TOTAL; off += NTHR * 16) {
    int o   = off + tid * 16;
    int row = o / ROWBYTES;
    int blk = (o >> 4) & MASK;
    int sb  = blk ^ (row & MASK & 7);
    const char* src = g + (size_t)row * strideBytes + (sb << 4);
    __builtin_amdgcn_global_load_lds((GV*)src, (LV*)(lds + o), 16, 0, 0);
  }
}

template<int ROWBYTES>
DEVFN short8 frag_ld(const char* lds, int row, int kbyte) {
  constexpr int MASK = (ROWBYTES >> 4) - 1;
  int blk = kbyte >> 4;
  int sb  = blk ^ (row & MASK & 7);
  return *(const short8*)(lds + row * ROWBYTES + (sb << 4));
}

DEVFN f32x4 mfma16(short8 a, short8 b, f32x4 c) {
  return __builtin_amdgcn_mfma_f32_16x16x32_bf16(a, b, c, 0, 0, 0);
}

// ---------------- merged prep kernels ----------------

__global__ void cvt3_kernel(const float* __restrict__ q, const float* __restrict__ k,
                            const float* __restrict__ v,
                            unsigned short* __restrict__ Xq,
                            unsigned short* __restrict__ Xk,
                            unsigned short* __restrict__ Xv, int n4) {
  int i = blockIdx.x * blockDim.x + threadIdx.x;
  if (i >= n4) return;
  const float* in = blockIdx.y == 0 ? q : (blockIdx.y == 1 ? k : v);
  unsigned short* out = blockIdx.y == 0 ? Xq : (blockIdx.y == 1 ? Xk : Xv);
  float4 val = ((const float4*)in)[i];
  ushort4 o;
  o.x = f32_bf16(val.x); o.y = f32_bf16(val.y);
  o.z = f32_bf16(val.z); o.w = f32_bf16(val.w);
  ((ushort4*)out)[i] = o;
}

// mask int32 {0,1} -> bf16 keep {1.0, 0.0}
__global__ void mask_prep_kernel(const int* __restrict__ m,
                                 unsigned short* __restrict__ ms, int n4) {
  int i = blockIdx.x * blockDim.x + threadIdx.x;
  if (i < n4) {
    int4 v = ((const int4*)m)[i];
    ushort4 o;
    o.x = v.x ? 0 : 0x3f80; o.y = v.y ? 0 : 0x3f80;
    o.z = v.z ? 0 : 0x3f80; o.w = v.w ? 0 : 0x3f80;
    ((ushort4*)ms)[i] = o;
  }
}

// all weight transposes in one launch: z 0-7 Wq, 8-15 Wk, 16-23 Wv, 24 Wo
__global__ void transpose_wall_kernel(const float* __restrict__ Wq,
                                      const float* __restrict__ Wk,
                                      const float* __restrict__ Wv,
                                      const float* __restrict__ Wo,
                                      unsigned short* __restrict__ WqT,
                                      unsigned short* __restrict__ WkT,
                                      unsigned short* __restrict__ WvT,
                                      unsigned short* __restrict__ WoT) {
  __shared__ float t[32][33];
  int z = blockIdx.z;
  const float* ip; unsigned short* op; int R, C;
  if (z < 8)       { ip = Wq + (size_t)z * Dd * Dd;        op = WqT + (size_t)z * Dd * Dd;        R = Dd; C = Dd; }
  else if (z < 16) { ip = Wk + (size_t)(z - 8) * Dd * Dd;  op = WkT + (size_t)(z - 8) * Dd * Dd;  R = Dd; C = Dd; }
  else if (z < 24) { ip = Wv + (size_t)(z - 16) * Dd * DVv; op = WvT + (size_t)(z - 16) * Dd * DVv; R = Dd; C = DVv; }
  else             { ip = Wo; op = WoT; R = Hh * DVv; C = DOo; }
  int c0 = blockIdx.x * 32, r0 = blockIdx.y * 32;
  if (c0 >= C || r0 >= R) return;
#pragma unroll
  for (int i = threadIdx.y; i < 32; i += 8)
    t[i][threadIdx.x] = ip[(size_t)(r0 + i) * C + c0 + threadIdx.x];
  __syncthreads();
#pragma unroll
  for (int i = threadIdx.y; i < 32; i += 8)
    op[(size_t)(c0 + i) * R + r0 + threadIdx.x] = f32_bf16(t[threadIdx.x][i]);
}

// ---------------- NT GEMM 128-tile ----------------
// EPI 0: bf16 out, head-strided rows. EPI 1: f32 out. EPI 2: bf16 out
// transposed to [b*Hh+h][col][n] (direct-VbT for the V projection).

template<int NCG, int EPI>
__global__ __launch_bounds__(256)
void gemm_nt_kernel(const unsigned short* __restrict__ A,
                    const unsigned short* __restrict__ BtAll,
                    void* __restrict__ Cb, int HeadsOut, int Ncols) {
  constexpr int BN = NCG * 32;
  constexpr int NL = 4 + BN / 32;
  __shared__ alignas(16) char As[2][16384];
  __shared__ alignas(16) char Bs[2][BN * 128];
  int tid = threadIdx.x, lane = tid & 63;
  int w = tid >> 6, wr = w >> 1, wc = w & 1;
  int tM = blockIdx.x, tN = blockIdx.y, h = blockIdx.z;
  const char* Ab  = (const char*)A + ((size_t)tM * 128) * 1024;
  const char* Btb = (const char*)BtAll + ((size_t)h * Ncols + tN * BN) * 1024;

  f32x4 acc[4][NCG] = {};

  stage_tile<128, 16384>(Ab, 1024, As[0], tid);
  stage_tile<128, BN * 128>(Btb, 1024, Bs[0], tid);
#pragma unroll
  for (int kk = 0; kk < 8; ++kk) {
    int cur = kk & 1;
    if (kk < 7) {
      stage_tile<128, 16384>(Ab + (kk + 1) * 128, 1024, As[cur ^ 1], tid);
      stage_tile<128, BN * 128>(Btb + (kk + 1) * 128, 1024, Bs[cur ^ 1], tid);
      wait_vmcnt<NL == 8 ? 8 : 6>();
    } else {
      wait_vmcnt<0>();
    }
    barrier_raw();
#pragma unroll
    for (int c = 0; c < 2; ++c) {
      short8 af[4], bf[NCG];
#pragma unroll
      for (int rg = 0; rg < 4; ++rg)
        af[rg] = frag_ld<128>(As[cur], wr * 64 + rg * 16 + (lane & 15),
                              c * 64 + (lane >> 4) * 16);
#pragma unroll
      for (int cg = 0; cg < NCG; ++cg)
        bf[cg] = frag_ld<128>(Bs[cur], wc * (NCG * 16) + cg * 16 + (lane & 15),
                              c * 64 + (lane >> 4) * 16);
#pragma unroll
      for (int rg = 0; rg < 4; ++rg)
#pragma unroll
        for (int cg = 0; cg < NCG; ++cg)
          acc[rg][cg] = mfma16(af[rg], bf[cg], acc[rg][cg]);
    }
    barrier_raw();
  }

#pragma unroll
  for (int rg = 0; rg < 4; ++rg)
#pragma unroll
    for (int cg = 0; cg < NCG; ++cg) {
      if constexpr (EPI == 2) {
        int grow0 = tM * 128 + wr * 64 + rg * 16 + (lane >> 4) * 4;
        int col   = tN * BN + wc * (NCG * 16) + cg * 16 + (lane & 15);
        int bq = grow0 >> 11, n0 = grow0 & 2047;
        ushort4 o;
        o.x = f32_bf16(acc[rg][cg][0]); o.y = f32_bf16(acc[rg][cg][1]);
        o.z = f32_bf16(acc[rg][cg][2]); o.w = f32_bf16(acc[rg][cg][3]);
        *(ushort4*)&((unsigned short*)Cb)[
            (((size_t)bq * Hh + h) * DVv + col) * 2048 + n0] = o;
      } else {
#pragma unroll
        for (int r = 0; r < 4; ++r) {
          int grow = tM * 128 + wr * 64 + rg * 16 + (lane >> 4) * 4 + r;
          int col  = tN * BN + wc * (NCG * 16) + cg * 16 + (lane & 15);
          size_t orow = ((size_t)(grow >> 11) * HeadsOut + h) * 2048 + (grow & 2047);
          if constexpr (EPI == 1)
            ((float*)Cb)[orow * Ncols + col] = acc[rg][cg][r];
          else
            ((unsigned short*)Cb)[orow * Ncols + col] = f32_bf16(acc[rg][cg][r]);
        }
      }
    }
}

// ---------------- S = Q*K^T + mask + scale -> attn f32 (d_out) ----------------
// One block per 128x128 S-tile. 8192 blocks, XCD-chunked swizzle.
// Epilogue (race-hardened with __syncthreads full fences): acc scattered
// (f32, XOR-swizzled) into the k-loop's 64 KB LDS (aliased only after a full
// block-wide drain), then re-read as float4 with coalesced ushort4 mask loads
// + float4 stores: 32 VMEM ops/thread, 512 B/wave segments.

__global__ __launch_bounds__(256)
void qk_attn_kernel(const unsigned short* __restrict__ Qb,
                    const unsigned short* __restrict__ Kb,
                    const unsigned short* __restrict__ ms,
                    float* __restrict__ attn_out) {
  __shared__ alignas(16) char LB[65536];
#define ASL(i) (LB + (i) * 16384)
#define BSL(i) (LB + 32768 + (i) * 16384)
  int tid = threadIdx.x, lane = tid & 63;
  int w = tid >> 6, wr = w >> 1, wc = w & 1;
  int fid = blockIdx.x;
  int orig = (fid & 7) * 1024 + (fid >> 3);     // XCD-chunked (8192 % 8 == 0)
  int tM = orig & 15, tN = (orig >> 4) & 15, bh = orig >> 8;

  const char* Ab  = (const char*)Qb + ((size_t)bh * Nn + tM * 128) * 1024;
  const char* Btb = (const char*)Kb + ((size_t)bh * Nn + tN * 128) * 1024;
  const float scale = 0.044194173824159216f;   // 1/sqrt(512)

  f32x4 acc[4][4] = {};

  stage_tile<128, 16384>(Ab, 1024, ASL(0), tid);
  stage_tile<128, 16384>(Btb, 1024, BSL(0), tid);
#pragma unroll
  for (int kk = 0; kk < 8; ++kk) {
    int cur = kk & 1;
    if (kk < 7) {
      stage_tile<128, 16384>(Ab + (kk + 1) * 128, 1024, ASL(cur ^ 1), tid);
      stage_tile<128, 16384>(Btb + (kk + 1) * 128, 1024, BSL(cur ^ 1), tid);
      wait_vmcnt<8>();
    } else {
      wait_vmcnt<0>();
    }
    barrier_raw();
#pragma unroll
    for (int c = 0; c < 2; ++c) {
      short8 af[4], bf[4];
#pragma unroll
      for (int rg = 0; rg < 4; ++rg)
        af[rg] = frag_ld<128>(ASL(cur), wr * 64 + rg * 16 + (lane & 15),
                              c * 64 + (lane >> 4) * 16);
#pragma unroll
      for (int cg = 0; cg < 4; ++cg)
        bf[cg] = frag_ld<128>(BSL(cur), wc * 64 + cg * 16 + (lane & 15),
                              c * 64 + (lane >> 4) * 16);
#pragma unroll
      for (int rg = 0; rg < 4; ++rg)
#pragma unroll
        for (int cg = 0; cg < 4; ++cg)
          acc[rg][cg] = mfma16(af[rg], bf[cg], acc[rg][cg]);
    }
    barrier_raw();
  }

  // Full block-wide drain before aliasing the k-loop LDS: after this fence
  // no wave has ANY outstanding LDS/VMEM op (raw s_barrier alone is not a
  // memory fence — this was R7's race).
  __syncthreads();

  // scatter acc (f32) into LDS, swizzled: addr = row*512 + ((c>>2 ^ row&31)<<4) + (c&3)*4
#pragma unroll
  for (int rg = 0; rg < 4; ++rg)
#pragma unroll
    for (int cg = 0; cg < 4; ++cg)
#pragma unroll
      for (int r = 0; r < 4; ++r) {
        int rowL = wr * 64 + rg * 16 + (lane >> 4) * 4 + r;
        int colL = wc * 64 + cg * 16 + (lane & 15);
        int addr = rowL * 512 + (((colL >> 2) ^ (rowL & 31)) << 4) + (colL & 3) * 4;
        *(float*)(LB + addr) = acc[rg][cg][r];
      }
  __syncthreads();

  // coalesced mask+scale+store: 8 rows x 128 cols per iteration
  int r0 = tid >> 5, c4 = (tid & 31) * 4;
#pragma unroll
  for (int it = 0; it < 16; ++it) {
    int row = it * 8 + r0;
    int addr = row * 512 + (((c4 >> 2) ^ (row & 31)) << 4);
    f32x4 vv = *(const f32x4*)(LB + addr);
    ushort4 mk = *(const ushort4*)(ms + (size_t)(tM * 128 + row) * Nn + tN * 128 + c4);
    f32x4 o;
    o[0] = vv[0] * scale * __builtin_bit_cast(float, (unsigned)mk.x << 16);
    o[1] = vv[1] * scale * __builtin_bit_cast(float, (unsigned)mk.y << 16);
    o[2] = vv[2] * scale * __builtin_bit_cast(float, (unsigned)mk.z << 16);
    o[3] = vv[3] * scale * __builtin_bit_cast(float, (unsigned)mk.w << 16);
    *(f32x4*)(attn_out + ((size_t)bh * Nn + tM * 128 + row) * Nn + tN * 128 + c4) = o;
  }
#undef ASL
#undef BSL
}

// ---------------- O = S * V  (S f32 from d_out, V^T bf16) ----------------
// 64-row M-tiles, grid (32, 32). BK=64, 32 k-steps. A reg-staged f32->bf16
// into swizzled LDS; B via global_load_lds. __syncthreads fences (the loop
// already full-drains vmcnt each step, so this costs nothing).

__global__ __launch_bounds__(256)
void pv_kernel(const float* __restrict__ attn,
               const unsigned short* __restrict__ VbT,
               unsigned short* __restrict__ QKV) {
  __shared__ alignas(16) char As[2][8192];
  __shared__ alignas(16) char Bs[2][8192];
  int tid = threadIdx.x, lane = tid & 63;
  int w = tid >> 6, wr = w >> 1, wc = w & 1;
  int tM = blockIdx.x, bh = blockIdx.y;
  int b = bh >> 3, h = bh & 7;

  int arow = tid >> 2, aseg = tid & 3;
  const float* Ag = attn + ((size_t)bh * Nn + (size_t)tM * 64 + arow) * Nn
                    + aseg * 16;
  const char* Btb = (const char*)VbT + (size_t)bh * DVv * Nn * 2;

  f32x4 acc[2][2] = {};

  auto packA = [&](float4 ar[4], char* dst) {
    short8 s0, s1;
#pragma unroll
    for (int e = 0; e < 4; ++e) {
      s0[e]     = (short)f32_bf16(ar[0][e]);
      s0[e + 4] = (short)f32_bf16(ar[1][e]);
      s1[e]     = (short)f32_bf16(ar[2][e]);
      s1[e + 4] = (short)f32_bf16(ar[3][e]);
    }
    int b0 = (aseg * 2) ^ (arow & 7), b1 = (aseg * 2 + 1) ^ (arow & 7);
    *(short8*)(dst + arow * 128 + (b0 << 4)) = s0;
    *(short8*)(dst + arow * 128 + (b1 << 4)) = s1;
  };

  {
    float4 ar[4];
#pragma unroll
    for (int i = 0; i < 4; ++i) ar[i] = ((const float4*)Ag)[i];
    stage_tile<128, 8192>(Btb, Nn * 2, Bs[0], tid);
    wait_vmcnt<0>();
    packA(ar, As[0]);
    __syncthreads();
  }

#pragma unroll 2
  for (int kk = 0; kk < 32; ++kk) {
    int cur = kk & 1;
    float4 ar[4];
    if (kk < 31) {
      const float* an = Ag + (kk + 1) * 64;
#pragma unroll
      for (int i = 0; i < 4; ++i) ar[i] = ((const float4*)an)[i];
      stage_tile<128, 8192>(Btb + (kk + 1) * 128, Nn * 2, Bs[cur ^ 1], tid);
    }
#pragma unroll
    for (int c = 0; c < 2; ++c) {
      short8 af[2], bf2[2];
#pragma unroll
      for (int rg = 0; rg < 2; ++rg)
        af[rg] = frag_ld<128>(As[cur], wr * 32 + rg * 16 + (lane & 15),
                              c * 64 + (lane >> 4) * 16);
#pragma unroll
      for (int cg = 0; cg < 2; ++cg)
        bf2[cg] = frag_ld<128>(Bs[cur], wc * 32 + cg * 16 + (lane & 15),
                               c * 64 + (lane >> 4) * 16);
#pragma unroll
      for (int rg = 0; rg < 2; ++rg)
#pragma unroll
        for (int cg = 0; cg < 2; ++cg)
          acc[rg][cg] = mfma16(af[rg], bf2[cg], acc[rg][cg]);
    }
    if (kk < 31) {
      wait_vmcnt<0>();
      packA(ar, As[cur ^ 1]);
    }
    __syncthreads();
  }

#pragma unroll
  for (int rg = 0; rg < 2; ++rg)
#pragma unroll
    for (int cg = 0; cg < 2; ++cg)
#pragma unroll
      for (int r = 0; r < 4; ++r) {
        int rowL = wr * 32 + rg * 16 + (lane >> 4) * 4 + r;
        int colL = wc * 32 + cg * 16 + (lane & 15);
        size_t grow = (size_t)tM * 64 + rowL;
        QKV[((size_t)b * Nn + grow) * (Hh * DVv) + h * DVv + colL] =
            f32_bf16(acc[rg][cg][r]);
      }
}

// ---------------- host ----------------

extern "C" void kernel_launch(void* const* d_in, const int* in_sizes, int n_in,
                              void* d_out, int out_size, void* d_ws, size_t ws_size,
                              hipStream_t stream) {
  const float* q    = (const float*)d_in[0];
  const float* k    = (const float*)d_in[1];
  const float* v    = (const float*)d_in[2];
  const int*   mask = (const int*)d_in[3];
  const float* Wq   = (const float*)d_in[4];
  const float* Wk   = (const float*)d_in[5];
  const float* Wv   = (const float*)d_in[6];
  const float* Wo   = (const float*)d_in[7];

  char* ws = (char*)d_ws;
  size_t off = 0;
  auto alloc = [&](size_t bytes) {
    char* p = ws + off;
    off += (bytes + 255) & ~(size_t)255;
    return p;
  };
  unsigned short* WqT  = (unsigned short*)alloc((size_t)Hh * Dd * Dd * 2);
  unsigned short* WkT  = (unsigned short*)alloc((size_t)Hh * Dd * Dd * 2);
  unsigned short* WvT  = (unsigned short*)alloc((size_t)Hh * DVv * Dd * 2);
  unsigned short* WoT  = (unsigned short*)alloc((size_t)DOo * Hh * DVv * 2);
  unsigned short* Xq   = (unsigned short*)alloc((size_t)Bb * Nn * Dd * 2);
  unsigned short* Xk   = (unsigned short*)alloc((size_t)Bb * Nn * Dd * 2);
  unsigned short* Xv   = (unsigned short*)alloc((size_t)Bb * Nn * Dd * 2);
  unsigned short* Qb   = (unsigned short*)alloc((size_t)Bb * Hh * Nn * Dd * 2);
  unsigned short* Kb   = (unsigned short*)alloc((size_t)Bb * Hh * Nn * Dd * 2);
  unsigned short* VbT  = (unsigned short*)alloc((size_t)Bb * Hh * DVv * Nn * 2);
  unsigned short* QKVb = (unsigned short*)alloc((size_t)Bb * Nn * Hh * DVv * 2);
  unsigned short* Ms   = (unsigned short*)alloc((size_t)Nn * Nn * 2);

  int n4 = Bb * Nn * Dd / 4;
  cvt3_kernel<<<dim3(n4 / 256, 3), dim3(256), 0, stream>>>(q, k, v, Xq, Xk, Xv, n4);
  mask_prep_kernel<<<dim3(Nn * Nn / 4 / 256), dim3(256), 0, stream>>>(mask, Ms, Nn * Nn / 4);
  transpose_wall_kernel<<<dim3(16, 16, 25), dim3(32, 8), 0, stream>>>(
      Wq, Wk, Wv, Wo, WqT, WkT, WvT, WoT);

  gemm_nt_kernel<4, 0><<<dim3(64, 4, Hh), dim3(256), 0, stream>>>(Xq, WqT, Qb, Hh, Dd);
  gemm_nt_kernel<4, 0><<<dim3(64, 4, Hh), dim3(256), 0, stream>>>(Xk, WkT, Kb, Hh, Dd);
  gemm_nt_kernel<2, 2><<<dim3(64, 1, Hh), dim3(256), 0, stream>>>(Xv, WvT, VbT, Hh, DVv);

  float* outp  = (float*)d_out;
  float* attnp = outp + (size_t)Bb * Nn * DOo;

  qk_attn_kernel<<<dim3(8192), dim3(256), 0, stream>>>(Qb, Kb, Ms, attnp);

  pv_kernel<<<dim3(32, 32), dim3(256), 0, stream>>>(attnp, VbT, QKVb);

  gemm_nt_kernel<4, 1><<<dim3(64, 4, 1), dim3(256), 0, stream>>>(QKVb, WoT, outp, 1, DOo);

  (void)in_sizes; (void)n_in; (void)out_size; (void)ws_size;
}